// Round 1
// baseline (418.356 us; speedup 1.0000x reference)
//
#include <hip/hip_runtime.h>
#include <hip/hip_bf16.h>

typedef short bf16x8 __attribute__((ext_vector_type(8)));  // 8 bf16 (4 VGPRs)
typedef float f32x4 __attribute__((ext_vector_type(4)));

#define S_LEN 2048
#define NHEAD 16
#define DMODEL 1024

__device__ __forceinline__ short f2bf(float f) {
  union { float f; unsigned u; } x; x.f = f;
  unsigned r = x.u + 0x7fffu + ((x.u >> 16) & 1u);  // RNE
  return (short)(r >> 16);
}

// C = A(MxK) @ W(KxN).  ABF: A is bf16 (else f32, converted on stage).
// MODE 0: C f32 row-major.  MODE 1: C bf16 scattered to [B,H,S,hd] (qkv layout).
template<bool ABF, int MODE>
__global__ __launch_bounds__(256) void gemm_k(const void* __restrict__ Ap,
                                              const float* __restrict__ Wp,
                                              void* __restrict__ Cp,
                                              int M, int N, int K) {
  __shared__ __align__(16) short Al[64][40];   // A tile, row-major [m][k], +8 pad
  __shared__ __align__(16) short Btl[64][40];  // W tile transposed [n][k], +8 pad
  const int tid = threadIdx.x;
  const int lane = tid & 63, w = tid >> 6;
  const int wm = w >> 1, wn = w & 1;
  const int lr = lane & 15, g = lane >> 4;
  const int m0 = blockIdx.y * 64, n0 = blockIdx.x * 64;

  f32x4 acc[2][2];
#pragma unroll
  for (int i = 0; i < 2; i++)
#pragma unroll
    for (int j = 0; j < 2; j++) acc[i][j] = (f32x4){0.f, 0.f, 0.f, 0.f};

  const int arow = tid >> 2, ac0 = (tid & 3) * 8;
  const int wrow = tid >> 3, wc0 = (tid & 7) * 8;

  for (int kk = 0; kk < K; kk += 32) {
    if (ABF) {
      const short* A = (const short*)Ap;
      bf16x8 v = *(const bf16x8*)&A[(size_t)(m0 + arow) * K + kk + ac0];
      *(bf16x8*)&Al[arow][ac0] = v;
    } else {
      const float* A = (const float*)Ap;
      const float* p = &A[(size_t)(m0 + arow) * K + kk + ac0];
      float4 v0 = *(const float4*)p;
      float4 v1 = *(const float4*)(p + 4);
      bf16x8 t;
      t[0] = f2bf(v0.x); t[1] = f2bf(v0.y); t[2] = f2bf(v0.z); t[3] = f2bf(v0.w);
      t[4] = f2bf(v1.x); t[5] = f2bf(v1.y); t[6] = f2bf(v1.z); t[7] = f2bf(v1.w);
      *(bf16x8*)&Al[arow][ac0] = t;
    }
    {
      const float* p = &Wp[(size_t)(kk + wrow) * N + n0 + wc0];
      float4 v0 = *(const float4*)p;
      float4 v1 = *(const float4*)(p + 4);
      Btl[wc0 + 0][wrow] = f2bf(v0.x);
      Btl[wc0 + 1][wrow] = f2bf(v0.y);
      Btl[wc0 + 2][wrow] = f2bf(v0.z);
      Btl[wc0 + 3][wrow] = f2bf(v0.w);
      Btl[wc0 + 4][wrow] = f2bf(v1.x);
      Btl[wc0 + 5][wrow] = f2bf(v1.y);
      Btl[wc0 + 6][wrow] = f2bf(v1.z);
      Btl[wc0 + 7][wrow] = f2bf(v1.w);
    }
    __syncthreads();
    bf16x8 af[2], bfr[2];
#pragma unroll
    for (int mi = 0; mi < 2; mi++) af[mi] = *(const bf16x8*)&Al[wm * 32 + mi * 16 + lr][g * 8];
#pragma unroll
    for (int nj = 0; nj < 2; nj++) bfr[nj] = *(const bf16x8*)&Btl[wn * 32 + nj * 16 + lr][g * 8];
#pragma unroll
    for (int mi = 0; mi < 2; mi++)
#pragma unroll
      for (int nj = 0; nj < 2; nj++)
        acc[mi][nj] = __builtin_amdgcn_mfma_f32_16x16x32_bf16(af[mi], bfr[nj], acc[mi][nj], 0, 0, 0);
    __syncthreads();
  }

#pragma unroll
  for (int mi = 0; mi < 2; mi++)
#pragma unroll
    for (int nj = 0; nj < 2; nj++)
#pragma unroll
      for (int r = 0; r < 4; r++) {
        int row = m0 + wm * 32 + mi * 16 + g * 4 + r;  // D: row=(lane>>4)*4+reg
        int col = n0 + wn * 32 + nj * 16 + lr;         // D: col=lane&15
        if (MODE == 0) {
          ((float*)Cp)[(size_t)row * N + col] = acc[mi][nj][r];
        } else {
          int bb = row >> 11, s = row & (S_LEN - 1);
          int hh = col >> 6, d = col & 63;
          ((short*)Cp)[(((size_t)bb * NHEAD + hh) * S_LEN + s) * 64 + d] = f2bf(acc[mi][nj][r]);
        }
      }
}

// Flash attention: grid (S/64, B*H), 256 threads (4 waves x 16 q-rows).
__global__ __launch_bounds__(256) void attn_k(const short* __restrict__ Qb,
                                              const short* __restrict__ Kb,
                                              const short* __restrict__ Vb,
                                              const int* __restrict__ mask,
                                              short* __restrict__ Ob) {
  __shared__ __align__(16) short Kl[32][80];     // K tile [k2][d], pad to 80
  __shared__ __align__(16) short Vtl[64][40];    // V tile transposed [d][k2]
  __shared__ __align__(16) short Pl[4][16][40];  // per-wave P bounce [q][k2]

  const int tid = threadIdx.x;
  const int lane = tid & 63, w = tid >> 6;
  const int lr = lane & 15, g = lane >> 4;
  const int bh = blockIdx.y;
  const int b = bh >> 4, h = bh & 15;
  const int qbase = blockIdx.x * 64;
  const size_t hoff = (size_t)bh * S_LEN * 64;

  const int qrow = qbase + w * 16 + lr;
  bf16x8 qf[2];
  qf[0] = *(const bf16x8*)&Qb[hoff + (size_t)qrow * 64 + g * 8];
  qf[1] = *(const bf16x8*)&Qb[hoff + (size_t)qrow * 64 + 32 + g * 8];

  float m_r[4], l_r[4];
  f32x4 o_acc[4];
#pragma unroll
  for (int r = 0; r < 4; r++) { m_r[r] = -1e30f; l_r[r] = 0.f; }
#pragma unroll
  for (int d = 0; d < 4; d++) o_acc[d] = (f32x4){0.f, 0.f, 0.f, 0.f};

  const int* maskb = mask + b * S_LEN;
  const int krow = tid >> 3, dcol = (tid & 7) * 8;

  for (int kb = 0; kb < S_LEN; kb += 32) {
    bf16x8 kv = *(const bf16x8*)&Kb[hoff + (size_t)(kb + krow) * 64 + dcol];
    *(bf16x8*)&Kl[krow][dcol] = kv;
    bf16x8 vv = *(const bf16x8*)&Vb[hoff + (size_t)(kb + krow) * 64 + dcol];
#pragma unroll
    for (int e = 0; e < 8; e++) Vtl[dcol + e][krow] = vv[e];
    __syncthreads();

    // scores = Q @ K^T : A=Q rows, B[d][k2]=K[k2][d]
    f32x4 sc0 = (f32x4){0.f, 0.f, 0.f, 0.f}, sc1 = sc0;
    {
      bf16x8 k00 = *(const bf16x8*)&Kl[lr][g * 8];
      bf16x8 k01 = *(const bf16x8*)&Kl[lr][32 + g * 8];
      sc0 = __builtin_amdgcn_mfma_f32_16x16x32_bf16(qf[0], k00, sc0, 0, 0, 0);
      sc0 = __builtin_amdgcn_mfma_f32_16x16x32_bf16(qf[1], k01, sc0, 0, 0, 0);
      bf16x8 k10 = *(const bf16x8*)&Kl[lr + 16][g * 8];
      bf16x8 k11 = *(const bf16x8*)&Kl[lr + 16][32 + g * 8];
      sc1 = __builtin_amdgcn_mfma_f32_16x16x32_bf16(qf[0], k10, sc1, 0, 0, 0);
      sc1 = __builtin_amdgcn_mfma_f32_16x16x32_bf16(qf[1], k11, sc1, 0, 0, 0);
    }

    const int mv0 = maskb[kb + lr];
    const int mv1 = maskb[kb + lr + 16];
    float pmax[4];
#pragma unroll
    for (int r = 0; r < 4; r++) {
      sc0[r] = mv0 ? sc0[r] * 0.125f : -1e30f;
      sc1[r] = mv1 ? sc1[r] * 0.125f : -1e30f;
      pmax[r] = fmaxf(sc0[r], sc1[r]);
    }
#pragma unroll
    for (int off = 1; off < 16; off <<= 1)
#pragma unroll
      for (int r = 0; r < 4; r++)
        pmax[r] = fmaxf(pmax[r], __shfl_xor(pmax[r], off));

    float p0[4], p1[4], rsum[4], scl[4];
#pragma unroll
    for (int r = 0; r < 4; r++) {
      float mn = fmaxf(m_r[r], pmax[r]);
      scl[r] = __expf(m_r[r] - mn);  // -1e30-(-1e30)=0 -> 1; no NaN path
      m_r[r] = mn;
      p0[r] = __expf(sc0[r] - mn);
      p1[r] = __expf(sc1[r] - mn);
      rsum[r] = p0[r] + p1[r];
    }
#pragma unroll
    for (int off = 1; off < 16; off <<= 1)
#pragma unroll
      for (int r = 0; r < 4; r++)
        rsum[r] += __shfl_xor(rsum[r], off);
#pragma unroll
    for (int r = 0; r < 4; r++) l_r[r] = l_r[r] * scl[r] + rsum[r];
#pragma unroll
    for (int d = 0; d < 4; d++)
#pragma unroll
      for (int r = 0; r < 4; r++) o_acc[d][r] *= scl[r];

    // P: D-layout (row=4g+r, col=lr) -> LDS -> A-layout (row=lr, k=8g+e)
#pragma unroll
    for (int r = 0; r < 4; r++) {
      Pl[w][g * 4 + r][lr] = f2bf(p0[r]);
      Pl[w][g * 4 + r][lr + 16] = f2bf(p1[r]);
    }
    __syncthreads();

    bf16x8 pf = *(const bf16x8*)&Pl[w][lr][g * 8];
#pragma unroll
    for (int dg = 0; dg < 4; dg++) {
      bf16x8 vf = *(const bf16x8*)&Vtl[lr + 16 * dg][g * 8];
      o_acc[dg] = __builtin_amdgcn_mfma_f32_16x16x32_bf16(pf, vf, o_acc[dg], 0, 0, 0);
    }
    __syncthreads();
  }

#pragma unroll
  for (int dg = 0; dg < 4; dg++)
#pragma unroll
    for (int r = 0; r < 4; r++) {
      int qr = qbase + w * 16 + g * 4 + r;
      int col = h * 64 + lr + 16 * dg;
      Ob[((size_t)b * S_LEN + qr) * DMODEL + col] = f2bf(o_acc[dg][r] / l_r[r]);
    }
}

extern "C" void kernel_launch(void* const* d_in, const int* in_sizes, int n_in,
                              void* d_out, int out_size, void* d_ws, size_t ws_size,
                              hipStream_t stream) {
  const float* query = (const float*)d_in[0];
  const float* key   = (const float*)d_in[1];
  const float* value = (const float*)d_in[2];
  const float* Wq = (const float*)d_in[3];
  const float* Wk = (const float*)d_in[4];
  const float* Wv = (const float*)d_in[5];
  const float* Wo = (const float*)d_in[6];
  const int* mask = (const int*)d_in[7];

  const int B = 2, M = B * S_LEN;
  size_t seg = (size_t)M * DMODEL * sizeof(short);  // 8 MB each
  short* qb = (short*)d_ws;
  short* kb = (short*)((char*)d_ws + seg);
  short* vb = (short*)((char*)d_ws + 2 * seg);
  short* ob = (short*)((char*)d_ws + 3 * seg);

  dim3 gblk(DMODEL / 64, M / 64);  // (16, 64)
  gemm_k<false, 1><<<gblk, 256, 0, stream>>>(query, Wq, qb, M, DMODEL, DMODEL);
  gemm_k<false, 1><<<gblk, 256, 0, stream>>>(key,   Wk, kb, M, DMODEL, DMODEL);
  gemm_k<false, 1><<<gblk, 256, 0, stream>>>(value, Wv, vb, M, DMODEL, DMODEL);

  dim3 ablk(S_LEN / 64, B * NHEAD);  // (32, 32)
  attn_k<<<ablk, 256, 0, stream>>>(qb, kb, vb, mask, ob);

  gemm_k<true, 0><<<gblk, 256, 0, stream>>>(ob, Wo, (float*)d_out, M, DMODEL, DMODEL);
}

// Round 2
// 241.404 us; speedup vs baseline: 1.7330x; 1.7330x over previous
//
#include <hip/hip_runtime.h>
#include <hip/hip_bf16.h>

typedef short bf16x8 __attribute__((ext_vector_type(8)));  // 8 bf16 (4 VGPRs)
typedef float f32x4 __attribute__((ext_vector_type(4)));

#define S_LEN 2048
#define NHEAD 16
#define DM 1024

__device__ __forceinline__ short f2bf(float f) {
  union { float f; unsigned u; } x; x.f = f;
  unsigned r = x.u + 0x7fffu + ((x.u >> 16) & 1u);  // RNE
  return (short)(r >> 16);
}

// ---------------- weight transpose+convert: T[n][k] = bf16(W[k][n]), 1024x1024
__global__ __launch_bounds__(256) void wtrans(const float* __restrict__ Wq, const float* __restrict__ Wk,
                                              const float* __restrict__ Wv, const float* __restrict__ Wo,
                                              short* Tq, short* Tk, short* Tv, short* To) {
  const int z = blockIdx.z;
  const float* W = (z == 0) ? Wq : (z == 1) ? Wk : (z == 2) ? Wv : Wo;
  short* T = (z == 0) ? Tq : (z == 1) ? Tk : (z == 2) ? Tv : To;
  __shared__ short Tl[64][72];
  const int tid = threadIdx.x;
  const int k0 = blockIdx.x * 64, n0 = blockIdx.y * 64;
  const int r = tid >> 2, c0 = (tid & 3) * 16;
#pragma unroll
  for (int j = 0; j < 4; j++) {
    float4 v = *(const float4*)&W[(size_t)(k0 + r) * DM + n0 + c0 + 4 * j];
    Tl[r][c0 + 4 * j + 0] = f2bf(v.x);
    Tl[r][c0 + 4 * j + 1] = f2bf(v.y);
    Tl[r][c0 + 4 * j + 2] = f2bf(v.z);
    Tl[r][c0 + 4 * j + 3] = f2bf(v.w);
  }
  __syncthreads();
  bf16x8 o0, o1;
#pragma unroll
  for (int j = 0; j < 8; j++) { o0[j] = Tl[c0 + j][r]; o1[j] = Tl[c0 + 8 + j][r]; }
  *(bf16x8*)&T[(size_t)(n0 + r) * DM + k0 + c0] = o0;
  *(bf16x8*)&T[(size_t)(n0 + r) * DM + k0 + c0 + 8] = o1;
}

// ---------------- GEMM: C(MxN) = A(MxK) @ B_op(KxN), B given as B_op^T[n][k].
// BM=128, BN=64, BK=64, 256 threads (4 waves, 2x2), acc 4x2 of 16x16.
// AM: 0=f32 row-major [m][k], 1=bf16 row-major [m][k]
// BMODE: 0=f32 row-major [n][k], 1=bf16 row-major [n][k], 2=f32 [k][n] (transpose-stage)
// CM: 0=f32 row-major, 1=bf16 scatter [bh][s][64], 2=bf16 scatter [bh][64][s]
template<int AM, int BMODE, int CM>
__global__ __launch_bounds__(256) void gemm2(const void* __restrict__ Ap, const void* __restrict__ Bp,
                                             void* __restrict__ Cp, int M, int N, int K) {
  __shared__ __align__(16) short Al[128][72];
  __shared__ __align__(16) short Bl[64][72];
  const int tid = threadIdx.x;
  const int lane = tid & 63, w = tid >> 6;
  const int wm = w >> 1, wn = w & 1;
  const int lr = lane & 15, g = lane >> 4;
  const int m0 = blockIdx.y * 128, n0 = blockIdx.x * 64;

  f32x4 acc[4][2];
#pragma unroll
  for (int i = 0; i < 4; i++)
#pragma unroll
    for (int j = 0; j < 2; j++) acc[i][j] = (f32x4){0.f, 0.f, 0.f, 0.f};

  const int ar = tid >> 1, ac = (tid & 1) * 32;  // A: 128 rows x 64k, 32 elems/thread
  const int br = tid >> 2, bc = (tid & 3) * 16;  // B: 64 rows x 64k, 16 elems/thread

  float4 la[8]; bf16x8 la8[4];
  float4 lb[4]; bf16x8 lb8[2];

#define LOADA(kk)                                                                        \
  do {                                                                                   \
    if (AM == 0) {                                                                       \
      const float* A = (const float*)Ap;                                                 \
      _Pragma("unroll") for (int j = 0; j < 8; j++)                                      \
          la[j] = *(const float4*)&A[(size_t)(m0 + ar) * K + (kk) + ac + 4 * j];         \
    } else {                                                                             \
      const short* A = (const short*)Ap;                                                 \
      _Pragma("unroll") for (int j = 0; j < 4; j++)                                      \
          la8[j] = *(const bf16x8*)&A[(size_t)(m0 + ar) * K + (kk) + ac + 8 * j];        \
    }                                                                                    \
  } while (0)

#define LOADB(kk)                                                                        \
  do {                                                                                   \
    if (BMODE == 0) {                                                                    \
      const float* B = (const float*)Bp;                                                 \
      _Pragma("unroll") for (int j = 0; j < 4; j++)                                      \
          lb[j] = *(const float4*)&B[(size_t)(n0 + br) * K + (kk) + bc + 4 * j];         \
    } else if (BMODE == 1) {                                                             \
      const short* B = (const short*)Bp;                                                 \
      _Pragma("unroll") for (int j = 0; j < 2; j++)                                      \
          lb8[j] = *(const bf16x8*)&B[(size_t)(n0 + br) * K + (kk) + bc + 8 * j];        \
    } else {                                                                             \
      const float* B = (const float*)Bp; /* B_op[k][n]: k row = br, n chunk = bc */      \
      _Pragma("unroll") for (int j = 0; j < 4; j++)                                      \
          lb[j] = *(const float4*)&B[(size_t)((kk) + br) * N + n0 + bc + 4 * j];         \
    }                                                                                    \
  } while (0)

  const int nsteps = K >> 6;
  LOADA(0); LOADB(0);

  for (int t = 0; t < nsteps; t++) {
    __syncthreads();
    // ---- write staged regs -> LDS
    if (AM == 0) {
#pragma unroll
      for (int j = 0; j < 4; j++) {
        float4 v0 = la[2 * j], v1 = la[2 * j + 1];
        bf16x8 tt;
        tt[0] = f2bf(v0.x); tt[1] = f2bf(v0.y); tt[2] = f2bf(v0.z); tt[3] = f2bf(v0.w);
        tt[4] = f2bf(v1.x); tt[5] = f2bf(v1.y); tt[6] = f2bf(v1.z); tt[7] = f2bf(v1.w);
        *(bf16x8*)&Al[ar][ac + 8 * j] = tt;
      }
    } else {
#pragma unroll
      for (int j = 0; j < 4; j++) *(bf16x8*)&Al[ar][ac + 8 * j] = la8[j];
    }
    if (BMODE == 0) {
#pragma unroll
      for (int j = 0; j < 2; j++) {
        float4 v0 = lb[2 * j], v1 = lb[2 * j + 1];
        bf16x8 tt;
        tt[0] = f2bf(v0.x); tt[1] = f2bf(v0.y); tt[2] = f2bf(v0.z); tt[3] = f2bf(v0.w);
        tt[4] = f2bf(v1.x); tt[5] = f2bf(v1.y); tt[6] = f2bf(v1.z); tt[7] = f2bf(v1.w);
        *(bf16x8*)&Bl[br][bc + 8 * j] = tt;
      }
    } else if (BMODE == 1) {
#pragma unroll
      for (int j = 0; j < 2; j++) *(bf16x8*)&Bl[br][bc + 8 * j] = lb8[j];
    } else {
#pragma unroll
      for (int j = 0; j < 4; j++) {
        float4 v = lb[j];
        Bl[bc + 4 * j + 0][br] = f2bf(v.x);
        Bl[bc + 4 * j + 1][br] = f2bf(v.y);
        Bl[bc + 4 * j + 2][br] = f2bf(v.z);
        Bl[bc + 4 * j + 3][br] = f2bf(v.w);
      }
    }
    __syncthreads();
    if (t + 1 < nsteps) { LOADA((t + 1) << 6); LOADB((t + 1) << 6); }
    // ---- compute
#pragma unroll
    for (int kc = 0; kc < 2; kc++) {
      bf16x8 af[4], bfr[2];
#pragma unroll
      for (int mt = 0; mt < 4; mt++) af[mt] = *(const bf16x8*)&Al[wm * 64 + mt * 16 + lr][kc * 32 + g * 8];
#pragma unroll
      for (int nt = 0; nt < 2; nt++) bfr[nt] = *(const bf16x8*)&Bl[wn * 32 + nt * 16 + lr][kc * 32 + g * 8];
#pragma unroll
      for (int mt = 0; mt < 4; mt++)
#pragma unroll
        for (int nt = 0; nt < 2; nt++)
          acc[mt][nt] = __builtin_amdgcn_mfma_f32_16x16x32_bf16(af[mt], bfr[nt], acc[mt][nt], 0, 0, 0);
    }
  }
#undef LOADA
#undef LOADB

#pragma unroll
  for (int mt = 0; mt < 4; mt++)
#pragma unroll
    for (int nt = 0; nt < 2; nt++)
#pragma unroll
      for (int r = 0; r < 4; r++) {
        int row = m0 + wm * 64 + mt * 16 + g * 4 + r;  // D: row=(lane>>4)*4+reg
        int col = n0 + wn * 32 + nt * 16 + lr;         // D: col=lane&15
        if (CM == 0) {
          ((float*)Cp)[(size_t)row * N + col] = acc[mt][nt][r];
        } else if (CM == 1) {  // row=token, col=dmodel -> [bh][s][64]
          int b = row >> 11, s = row & (S_LEN - 1);
          int h = col >> 6, d = col & 63;
          ((short*)Cp)[(((size_t)(b * NHEAD + h)) * S_LEN + s) * 64 + d] = f2bf(acc[mt][nt][r]);
        } else {  // row=dmodel, col=token -> [bh][64][s]
          int h = row >> 6, d = row & 63;
          int b = col >> 11, s = col & (S_LEN - 1);
          ((short*)Cp)[(((size_t)(b * NHEAD + h)) * 64 + d) * S_LEN + s] = f2bf(acc[mt][nt][r]);
        }
      }
}

// ---------------- Flash attention: grid (S/64, B*H), 256 thr (4 waves x 16 q).
// Q,K: [bh][s][64] bf16.  V^T: [bh][64][s] bf16.  KVBLK=64.
__global__ __launch_bounds__(256) void attn2(const short* __restrict__ Qb,
                                             const short* __restrict__ Kb,
                                             const short* __restrict__ VbT,
                                             const int* __restrict__ mask,
                                             short* __restrict__ Ob) {
  __shared__ __align__(16) short Kl[64][72];    // [k][d]
  __shared__ __align__(16) short Vtl[64][72];   // [d][k]
  __shared__ __align__(16) short Pl[4][16][72]; // per-wave [q][k]
  __shared__ int Ml[64];

  const int tid = threadIdx.x;
  const int lane = tid & 63, w = tid >> 6;
  const int lr = lane & 15, g = lane >> 4;
  const int bh = blockIdx.y;
  const int b = bh >> 4, h = bh & 15;
  const int qbase = blockIdx.x * 64;
  const size_t hoff = (size_t)bh * S_LEN * 64;

  const int qrow = qbase + w * 16 + lr;
  bf16x8 qf[2];
  qf[0] = *(const bf16x8*)&Qb[hoff + (size_t)qrow * 64 + g * 8];
  qf[1] = *(const bf16x8*)&Qb[hoff + (size_t)qrow * 64 + 32 + g * 8];

  float m_r[4], l_r[4];
  f32x4 o_acc[4];
#pragma unroll
  for (int r = 0; r < 4; r++) { m_r[r] = -1e30f; l_r[r] = 0.f; }
#pragma unroll
  for (int d = 0; d < 4; d++) o_acc[d] = (f32x4){0.f, 0.f, 0.f, 0.f};

  const int* maskb = mask + b * S_LEN;
  const int sr = tid >> 2, sc = (tid & 3) * 16;

  for (int kb = 0; kb < S_LEN; kb += 64) {
    __syncthreads();  // prior PV reads done before overwrite
    *(bf16x8*)&Kl[sr][sc]      = *(const bf16x8*)&Kb[hoff + (size_t)(kb + sr) * 64 + sc];
    *(bf16x8*)&Kl[sr][sc + 8]  = *(const bf16x8*)&Kb[hoff + (size_t)(kb + sr) * 64 + sc + 8];
    *(bf16x8*)&Vtl[sr][sc]     = *(const bf16x8*)&VbT[hoff + (size_t)sr * S_LEN + kb + sc];
    *(bf16x8*)&Vtl[sr][sc + 8] = *(const bf16x8*)&VbT[hoff + (size_t)sr * S_LEN + kb + sc + 8];
    if (tid < 64) Ml[tid] = maskb[kb + tid];
    __syncthreads();

    // ---- scores = Q @ K^T for 16q x 64k per wave
    f32x4 sc4[4];
#pragma unroll
    for (int nt = 0; nt < 4; nt++) sc4[nt] = (f32x4){0.f, 0.f, 0.f, 0.f};
#pragma unroll
    for (int nt = 0; nt < 4; nt++) {
      bf16x8 k0 = *(const bf16x8*)&Kl[nt * 16 + lr][g * 8];
      bf16x8 k1 = *(const bf16x8*)&Kl[nt * 16 + lr][32 + g * 8];
      sc4[nt] = __builtin_amdgcn_mfma_f32_16x16x32_bf16(qf[0], k0, sc4[nt], 0, 0, 0);
      sc4[nt] = __builtin_amdgcn_mfma_f32_16x16x32_bf16(qf[1], k1, sc4[nt], 0, 0, 0);
    }

    int mv[4];
#pragma unroll
    for (int nt = 0; nt < 4; nt++) mv[nt] = Ml[nt * 16 + lr];

    float pmax[4];
#pragma unroll
    for (int r = 0; r < 4; r++) pmax[r] = -1e30f;
#pragma unroll
    for (int nt = 0; nt < 4; nt++)
#pragma unroll
      for (int r = 0; r < 4; r++) {
        float s = mv[nt] ? sc4[nt][r] * 0.125f : -1e30f;
        sc4[nt][r] = s;
        pmax[r] = fmaxf(pmax[r], s);
      }
#pragma unroll
    for (int off = 1; off < 16; off <<= 1)
#pragma unroll
      for (int r = 0; r < 4; r++) pmax[r] = fmaxf(pmax[r], __shfl_xor(pmax[r], off));

    float p[4][4], rsum[4], scl[4];
#pragma unroll
    for (int r = 0; r < 4; r++) {
      float mn = fmaxf(m_r[r], pmax[r]);
      scl[r] = __expf(m_r[r] - mn);
      m_r[r] = mn;
      rsum[r] = 0.f;
#pragma unroll
      for (int nt = 0; nt < 4; nt++) {
        p[nt][r] = __expf(sc4[nt][r] - mn);
        rsum[r] += p[nt][r];
      }
    }
#pragma unroll
    for (int off = 1; off < 16; off <<= 1)
#pragma unroll
      for (int r = 0; r < 4; r++) rsum[r] += __shfl_xor(rsum[r], off);
#pragma unroll
    for (int r = 0; r < 4; r++) l_r[r] = l_r[r] * scl[r] + rsum[r];
#pragma unroll
    for (int d = 0; d < 4; d++)
#pragma unroll
      for (int r = 0; r < 4; r++) o_acc[d][r] *= scl[r];

    // ---- P -> per-wave LDS (no barrier needed)
#pragma unroll
    for (int nt = 0; nt < 4; nt++)
#pragma unroll
      for (int r = 0; r < 4; r++) Pl[w][g * 4 + r][nt * 16 + lr] = f2bf(p[nt][r]);

    bf16x8 pf0 = *(const bf16x8*)&Pl[w][lr][g * 8];
    bf16x8 pf1 = *(const bf16x8*)&Pl[w][lr][32 + g * 8];
#pragma unroll
    for (int dg = 0; dg < 4; dg++) {
      bf16x8 vf0 = *(const bf16x8*)&Vtl[dg * 16 + lr][g * 8];
      bf16x8 vf1 = *(const bf16x8*)&Vtl[dg * 16 + lr][32 + g * 8];
      o_acc[dg] = __builtin_amdgcn_mfma_f32_16x16x32_bf16(pf0, vf0, o_acc[dg], 0, 0, 0);
      o_acc[dg] = __builtin_amdgcn_mfma_f32_16x16x32_bf16(pf1, vf1, o_acc[dg], 0, 0, 0);
    }
  }

#pragma unroll
  for (int dg = 0; dg < 4; dg++)
#pragma unroll
    for (int r = 0; r < 4; r++) {
      int qr = qbase + w * 16 + g * 4 + r;
      int col = h * 64 + dg * 16 + lr;
      Ob[((size_t)b * S_LEN + qr) * DM + col] = f2bf(o_acc[dg][r] / l_r[r]);
    }
}

extern "C" void kernel_launch(void* const* d_in, const int* in_sizes, int n_in,
                              void* d_out, int out_size, void* d_ws, size_t ws_size,
                              hipStream_t stream) {
  const float* query = (const float*)d_in[0];
  const float* key   = (const float*)d_in[1];
  const float* value = (const float*)d_in[2];
  const float* Wq = (const float*)d_in[3];
  const float* Wk = (const float*)d_in[4];
  const float* Wv = (const float*)d_in[5];
  const float* Wo = (const float*)d_in[6];
  const int* mask = (const int*)d_in[7];

  char* ws = (char*)d_ws;
  const size_t MB = 1 << 20;
  const bool big = ws_size >= 40 * MB;

  short* Qb  = (short*)(ws);
  short* Kb  = (short*)(ws + 8 * MB);
  short* VbT = (short*)(ws + 16 * MB);
  short* WqT = (short*)(ws + 24 * MB);
  short* WkT = (short*)(ws + 26 * MB);
  short* WvT = (short*)(ws + 28 * MB);
  short* WoT = (short*)(ws + 30 * MB);          // only if big
  short* Ob  = big ? (short*)(ws + 32 * MB)     // distinct
                   : (short*)(ws + 24 * MB);    // alias dead WqT/WkT/WvT

  dim3 tgrid(16, 16, big ? 4 : 3);
  wtrans<<<tgrid, 256, 0, stream>>>(Wq, Wk, Wv, Wo, WqT, WkT, WvT, big ? WoT : WqT);

  dim3 gq(DM / 64, (2 * S_LEN) / 128);  // (16, 32)
  gemm2<0, 1, 1><<<gq, 256, 0, stream>>>(query, WqT, Qb, 2 * S_LEN, DM, DM);
  gemm2<0, 1, 1><<<gq, 256, 0, stream>>>(key,   WkT, Kb, 2 * S_LEN, DM, DM);
  dim3 gv((2 * S_LEN) / 64, DM / 128);  // (64, 8)
  gemm2<1, 0, 2><<<gv, 256, 0, stream>>>(WvT, value, VbT, DM, 2 * S_LEN, DM);

  dim3 ag(S_LEN / 64, 2 * NHEAD);  // (32, 32)
  attn2<<<ag, 256, 0, stream>>>(Qb, Kb, VbT, mask, Ob);

  if (big) gemm2<1, 1, 0><<<gq, 256, 0, stream>>>(Ob, WoT, (float*)d_out, 2 * S_LEN, DM, DM);
  else     gemm2<1, 2, 0><<<gq, 256, 0, stream>>>(Ob, Wo,  (float*)d_out, 2 * S_LEN, DM, DM);
}

// Round 3
// 195.975 us; speedup vs baseline: 2.1347x; 1.2318x over previous
//
#include <hip/hip_runtime.h>
#include <hip/hip_bf16.h>

typedef short bf16x8 __attribute__((ext_vector_type(8)));  // 8 bf16 (4 VGPRs)
typedef float f32x4 __attribute__((ext_vector_type(4)));

#define S_LEN 2048
#define NHEAD 16
#define DM 1024

#if __has_builtin(__builtin_amdgcn_exp2f)
#define EXP2(x) __builtin_amdgcn_exp2f(x)
#else
#define EXP2(x) exp2f(x)
#endif

__device__ __forceinline__ short f2bf(float f) {
  union { float f; unsigned u; } x; x.f = f;
  unsigned r = x.u + 0x7fffu + ((x.u >> 16) & 1u);  // RNE
  return (short)(r >> 16);
}

__device__ __forceinline__ void gload16(const void* g, void* l) {
  __builtin_amdgcn_global_load_lds(
      (const __attribute__((address_space(1))) void*)g,
      (__attribute__((address_space(3))) void*)l, 16, 0, 0);
}

// ---------------- weight transpose+convert: T[n][k] = bf16(W[k][n]), 1024x1024
__global__ __launch_bounds__(256) void wtrans(const float* __restrict__ Wq, const float* __restrict__ Wk,
                                              const float* __restrict__ Wv, const float* __restrict__ Wo,
                                              short* Tq, short* Tk, short* Tv, short* To) {
  const int z = blockIdx.z;
  const float* W = (z == 0) ? Wq : (z == 1) ? Wk : (z == 2) ? Wv : Wo;
  short* T = (z == 0) ? Tq : (z == 1) ? Tk : (z == 2) ? Tv : To;
  __shared__ short Tl[64][72];
  const int tid = threadIdx.x;
  const int k0 = blockIdx.x * 64, n0 = blockIdx.y * 64;
  const int r = tid >> 2, c0 = (tid & 3) * 16;
#pragma unroll
  for (int j = 0; j < 4; j++) {
    float4 v = *(const float4*)&W[(size_t)(k0 + r) * DM + n0 + c0 + 4 * j];
    Tl[r][c0 + 4 * j + 0] = f2bf(v.x);
    Tl[r][c0 + 4 * j + 1] = f2bf(v.y);
    Tl[r][c0 + 4 * j + 2] = f2bf(v.z);
    Tl[r][c0 + 4 * j + 3] = f2bf(v.w);
  }
  __syncthreads();
  bf16x8 o0, o1;
#pragma unroll
  for (int j = 0; j < 8; j++) { o0[j] = Tl[c0 + j][r]; o1[j] = Tl[c0 + 8 + j][r]; }
  *(bf16x8*)&T[(size_t)(n0 + r) * DM + k0 + c0] = o0;
  *(bf16x8*)&T[(size_t)(n0 + r) * DM + k0 + c0 + 8] = o1;
}

// ---------------- GEMM: C(MxN) = A(MxK) @ B_op(KxN), B given as B_op^T[n][k].
// BM=128, BN=64, BK=64, 256 threads (4 waves, 2x2), acc 4x2 of 16x16.
// AM: 0=f32 row-major [m][k], 1=bf16 row-major [m][k]
// BMODE: 0=f32 row-major [n][k], 1=bf16 row-major [n][k], 2=f32 [k][n] (transpose-stage)
// CM: 0=f32 row-major, 1=bf16 scatter [bh][s][64], 2=bf16 scatter [bh][64][s],
//     3=like 1 but scaled by 0.125*log2(e)  (Q projection)
template<int AM, int BMODE, int CM>
__global__ __launch_bounds__(256) void gemm2(const void* __restrict__ Ap, const void* __restrict__ Bp,
                                             void* __restrict__ Cp, int M, int N, int K) {
  __shared__ __align__(16) short Al[128][72];
  __shared__ __align__(16) short Bl[64][72];
  const int tid = threadIdx.x;
  const int lane = tid & 63, w = tid >> 6;
  const int wm = w >> 1, wn = w & 1;
  const int lr = lane & 15, g = lane >> 4;
  const int m0 = blockIdx.y * 128, n0 = blockIdx.x * 64;

  f32x4 acc[4][2];
#pragma unroll
  for (int i = 0; i < 4; i++)
#pragma unroll
    for (int j = 0; j < 2; j++) acc[i][j] = (f32x4){0.f, 0.f, 0.f, 0.f};

  const int ar = tid >> 1, ac = (tid & 1) * 32;
  const int br = tid >> 2, bc = (tid & 3) * 16;

  float4 la[8]; bf16x8 la8[4];
  float4 lb[4]; bf16x8 lb8[2];

#define LOADA(kk)                                                                        \
  do {                                                                                   \
    if (AM == 0) {                                                                       \
      const float* A = (const float*)Ap;                                                 \
      _Pragma("unroll") for (int j = 0; j < 8; j++)                                      \
          la[j] = *(const float4*)&A[(size_t)(m0 + ar) * K + (kk) + ac + 4 * j];         \
    } else {                                                                             \
      const short* A = (const short*)Ap;                                                 \
      _Pragma("unroll") for (int j = 0; j < 4; j++)                                      \
          la8[j] = *(const bf16x8*)&A[(size_t)(m0 + ar) * K + (kk) + ac + 8 * j];        \
    }                                                                                    \
  } while (0)

#define LOADB(kk)                                                                        \
  do {                                                                                   \
    if (BMODE == 0) {                                                                    \
      const float* B = (const float*)Bp;                                                 \
      _Pragma("unroll") for (int j = 0; j < 4; j++)                                      \
          lb[j] = *(const float4*)&B[(size_t)(n0 + br) * K + (kk) + bc + 4 * j];         \
    } else if (BMODE == 1) {                                                             \
      const short* B = (const short*)Bp;                                                 \
      _Pragma("unroll") for (int j = 0; j < 2; j++)                                      \
          lb8[j] = *(const bf16x8*)&B[(size_t)(n0 + br) * K + (kk) + bc + 8 * j];        \
    } else {                                                                             \
      const float* B = (const float*)Bp;                                                 \
      _Pragma("unroll") for (int j = 0; j < 4; j++)                                      \
          lb[j] = *(const float4*)&B[(size_t)((kk) + br) * N + n0 + bc + 4 * j];         \
    }                                                                                    \
  } while (0)

  const int nsteps = K >> 6;
  LOADA(0); LOADB(0);

  for (int t = 0; t < nsteps; t++) {
    __syncthreads();
    if (AM == 0) {
#pragma unroll
      for (int j = 0; j < 4; j++) {
        float4 v0 = la[2 * j], v1 = la[2 * j + 1];
        bf16x8 tt;
        tt[0] = f2bf(v0.x); tt[1] = f2bf(v0.y); tt[2] = f2bf(v0.z); tt[3] = f2bf(v0.w);
        tt[4] = f2bf(v1.x); tt[5] = f2bf(v1.y); tt[6] = f2bf(v1.z); tt[7] = f2bf(v1.w);
        *(bf16x8*)&Al[ar][ac + 8 * j] = tt;
      }
    } else {
#pragma unroll
      for (int j = 0; j < 4; j++) *(bf16x8*)&Al[ar][ac + 8 * j] = la8[j];
    }
    if (BMODE == 0) {
#pragma unroll
      for (int j = 0; j < 2; j++) {
        float4 v0 = lb[2 * j], v1 = lb[2 * j + 1];
        bf16x8 tt;
        tt[0] = f2bf(v0.x); tt[1] = f2bf(v0.y); tt[2] = f2bf(v0.z); tt[3] = f2bf(v0.w);
        tt[4] = f2bf(v1.x); tt[5] = f2bf(v1.y); tt[6] = f2bf(v1.z); tt[7] = f2bf(v1.w);
        *(bf16x8*)&Bl[br][bc + 8 * j] = tt;
      }
    } else if (BMODE == 1) {
#pragma unroll
      for (int j = 0; j < 2; j++) *(bf16x8*)&Bl[br][bc + 8 * j] = lb8[j];
    } else {
#pragma unroll
      for (int j = 0; j < 4; j++) {
        float4 v = lb[j];
        Bl[bc + 4 * j + 0][br] = f2bf(v.x);
        Bl[bc + 4 * j + 1][br] = f2bf(v.y);
        Bl[bc + 4 * j + 2][br] = f2bf(v.z);
        Bl[bc + 4 * j + 3][br] = f2bf(v.w);
      }
    }
    __syncthreads();
    if (t + 1 < nsteps) { LOADA((t + 1) << 6); LOADB((t + 1) << 6); }
#pragma unroll
    for (int kc = 0; kc < 2; kc++) {
      bf16x8 af[4], bfr[2];
#pragma unroll
      for (int mt = 0; mt < 4; mt++) af[mt] = *(const bf16x8*)&Al[wm * 64 + mt * 16 + lr][kc * 32 + g * 8];
#pragma unroll
      for (int nt = 0; nt < 2; nt++) bfr[nt] = *(const bf16x8*)&Bl[wn * 32 + nt * 16 + lr][kc * 32 + g * 8];
#pragma unroll
      for (int mt = 0; mt < 4; mt++)
#pragma unroll
        for (int nt = 0; nt < 2; nt++)
          acc[mt][nt] = __builtin_amdgcn_mfma_f32_16x16x32_bf16(af[mt], bfr[nt], acc[mt][nt], 0, 0, 0);
    }
  }
#undef LOADA
#undef LOADB

#pragma unroll
  for (int mt = 0; mt < 4; mt++)
#pragma unroll
    for (int nt = 0; nt < 2; nt++)
#pragma unroll
      for (int r = 0; r < 4; r++) {
        int row = m0 + wm * 64 + mt * 16 + g * 4 + r;
        int col = n0 + wn * 32 + nt * 16 + lr;
        if (CM == 0) {
          ((float*)Cp)[(size_t)row * N + col] = acc[mt][nt][r];
        } else if (CM == 1 || CM == 3) {
          float v = (CM == 3) ? acc[mt][nt][r] * 0.18033688011f : acc[mt][nt][r];
          int b = row >> 11, s = row & (S_LEN - 1);
          int h = col >> 6, d = col & 63;
          ((short*)Cp)[(((size_t)(b * NHEAD + h)) * S_LEN + s) * 64 + d] = f2bf(v);
        } else {
          int h = row >> 6, d = row & 63;
          int b = col >> 11, s = col & (S_LEN - 1);
          ((short*)Cp)[(((size_t)(b * NHEAD + h)) * 64 + d) * S_LEN + s] = f2bf(acc[mt][nt][r]);
        }
      }
}

// ---------------- Flash attention v3.
// Q pre-scaled by 0.125*log2e; softmax = exp2, max-free (scores bounded),
// deferred row-sum. QBLK=256 (8 waves x 32 q), KVBLK=64, dbuf K/V via
// global_load_lds with pre-swizzled source; all LDS tiles [*][64] shorts
// (128B rows) with byte ^= (row&7)<<4 XOR swizzle (short idx ^= (row&7)<<3).
// Q,K: [bh][s][64] bf16.  V^T: [bh][64][s] bf16.
__global__ __launch_bounds__(512, 2) void attn3(const short* __restrict__ Qb,
                                                const short* __restrict__ Kb,
                                                const short* __restrict__ VbT,
                                                const int* __restrict__ mask,
                                                short* __restrict__ Ob) {
  __shared__ __align__(16) short Kl[2][64][64];
  __shared__ __align__(16) short Vl[2][64][64];
  __shared__ __align__(16) short Pl[8][32][64];

  const int tid = threadIdx.x;
  const int lane = tid & 63, w = tid >> 6;        // 8 waves
  const int lr = lane & 15, g = lane >> 4;
  const int bh = blockIdx.y, b = bh >> 4, h = bh & 15;
  const int qbase = blockIdx.x * 256;
  const size_t hoff = (size_t)bh * S_LEN * 64;

  // Q fragments: 32 q-rows per wave (2 x 16-frag), 64 d (2 k-halves)
  bf16x8 qf[2][2];
#pragma unroll
  for (int qfr = 0; qfr < 2; qfr++)
#pragma unroll
    for (int kh = 0; kh < 2; kh++)
      qf[qfr][kh] = *(const bf16x8*)&Qb[hoff + (size_t)(qbase + w * 32 + qfr * 16 + lr) * 64 + kh * 32 + g * 8];

  f32x4 o_acc[2][4];
  float lsum[2][4];
#pragma unroll
  for (int qfr = 0; qfr < 2; qfr++) {
#pragma unroll
    for (int dg = 0; dg < 4; dg++) o_acc[qfr][dg] = (f32x4){0.f, 0.f, 0.f, 0.f};
#pragma unroll
    for (int r = 0; r < 4; r++) lsum[qfr][r] = 0.f;
  }

  const int* maskb = mask + b * S_LEN;
  // staging geometry: wave w stages K rows [w*8, w*8+8) and V rows [w*8, w*8+8)
  // lane l -> row w*8 + (l>>3), source col8 = (l&7) ^ (l>>3)  (pre-swizzle)
  const int srow = lane >> 3;
  const int scol8 = (lane & 7) ^ srow;
  const short* gK = Kb + hoff + (size_t)(w * 8 + srow) * 64 + 8 * scol8;
  const short* gV = VbT + hoff + (size_t)(w * 8 + srow) * S_LEN + 8 * scol8;

  const int NT = S_LEN / 64;
  // prologue: stage tile 0 into buf 0
  gload16(gK, (void*)&Kl[0][w * 8][0]);
  gload16(gV + 0, (void*)&Vl[0][w * 8][0]);

  for (int t = 0; t < NT; t++) {
    const int kb = t * 64;
    const int bufi = t & 1;
    __syncthreads();  // drains vmcnt: tile t resident; all reads of buf^1 done
    if (t + 1 < NT) {
      gload16(gK + (size_t)(kb + 64) * 64, (void*)&Kl[bufi ^ 1][w * 8][0]);
      gload16(gV + kb + 64, (void*)&Vl[bufi ^ 1][w * 8][0]);
    }

    float bias[4];
#pragma unroll
    for (int nt = 0; nt < 4; nt++) bias[nt] = maskb[kb + 16 * nt + lr] ? 0.f : -1e30f;

    // ---- QK^T
    bf16x8 kfr[4][2];
#pragma unroll
    for (int nt = 0; nt < 4; nt++)
#pragma unroll
      for (int kh = 0; kh < 2; kh++)
        kfr[nt][kh] = *(const bf16x8*)&Kl[bufi][nt * 16 + lr][8 * ((4 * kh + g) ^ (lr & 7))];

    f32x4 s[2][4];
#pragma unroll
    for (int qfr = 0; qfr < 2; qfr++)
#pragma unroll
      for (int nt = 0; nt < 4; nt++) s[qfr][nt] = (f32x4){0.f, 0.f, 0.f, 0.f};
#pragma unroll
    for (int qfr = 0; qfr < 2; qfr++)
#pragma unroll
      for (int nt = 0; nt < 4; nt++) {
        s[qfr][nt] = __builtin_amdgcn_mfma_f32_16x16x32_bf16(qf[qfr][0], kfr[nt][0], s[qfr][nt], 0, 0, 0);
        s[qfr][nt] = __builtin_amdgcn_mfma_f32_16x16x32_bf16(qf[qfr][1], kfr[nt][1], s[qfr][nt], 0, 0, 0);
      }

    // V frags (independent of P; latency hides under softmax)
    bf16x8 vfr[4][2];
#pragma unroll
    for (int dg = 0; dg < 4; dg++)
#pragma unroll
      for (int kh = 0; kh < 2; kh++)
        vfr[dg][kh] = *(const bf16x8*)&Vl[bufi][dg * 16 + lr][8 * ((4 * kh + g) ^ (lr & 7))];

    // ---- softmax: p = exp2(s + bias); deferred row-sum; P -> per-wave LDS
#pragma unroll
    for (int qfr = 0; qfr < 2; qfr++)
#pragma unroll
      for (int nt = 0; nt < 4; nt++)
#pragma unroll
        for (int r = 0; r < 4; r++) {
          float p = EXP2(s[qfr][nt][r] + bias[nt]);
          lsum[qfr][r] += p;
          union { float f; unsigned u; } cv; cv.f = p;
          unsigned short pb = (unsigned short)((cv.u + 0x7fffu) >> 16);
          int q = qfr * 16 + g * 4 + r;
          Pl[w][q][(16 * nt + lr) ^ ((q & 7) << 3)] = (short)pb;
        }

    // ---- PV
#pragma unroll
    for (int qfr = 0; qfr < 2; qfr++) {
      bf16x8 pf[2];
#pragma unroll
      for (int kh = 0; kh < 2; kh++)
        pf[kh] = *(const bf16x8*)&Pl[w][qfr * 16 + lr][8 * ((4 * kh + g) ^ (lr & 7))];
#pragma unroll
      for (int dg = 0; dg < 4; dg++) {
        o_acc[qfr][dg] = __builtin_amdgcn_mfma_f32_16x16x32_bf16(pf[0], vfr[dg][0], o_acc[qfr][dg], 0, 0, 0);
        o_acc[qfr][dg] = __builtin_amdgcn_mfma_f32_16x16x32_bf16(pf[1], vfr[dg][1], o_acc[qfr][dg], 0, 0, 0);
      }
    }
  }

  // ---- epilogue: reduce lsum across the 16 k-lanes, normalize, store
#pragma unroll
  for (int qfr = 0; qfr < 2; qfr++)
#pragma unroll
    for (int r = 0; r < 4; r++) {
      float l = lsum[qfr][r];
#pragma unroll
      for (int off = 1; off < 16; off <<= 1) l += __shfl_xor(l, off);
      float inv = 1.f / l;
      int qr = qbase + w * 32 + qfr * 16 + g * 4 + r;
#pragma unroll
      for (int dg = 0; dg < 4; dg++) {
        int col = h * 64 + dg * 16 + lr;
        Ob[((size_t)b * S_LEN + qr) * DM + col] = f2bf(o_acc[qfr][dg][r] * inv);
      }
    }
}

extern "C" void kernel_launch(void* const* d_in, const int* in_sizes, int n_in,
                              void* d_out, int out_size, void* d_ws, size_t ws_size,
                              hipStream_t stream) {
  const float* query = (const float*)d_in[0];
  const float* key   = (const float*)d_in[1];
  const float* value = (const float*)d_in[2];
  const float* Wq = (const float*)d_in[3];
  const float* Wk = (const float*)d_in[4];
  const float* Wv = (const float*)d_in[5];
  const float* Wo = (const float*)d_in[6];
  const int* mask = (const int*)d_in[7];

  char* ws = (char*)d_ws;
  const size_t MB = 1 << 20;
  const bool big = ws_size >= 40 * MB;

  short* Qb  = (short*)(ws);
  short* Kb  = (short*)(ws + 8 * MB);
  short* VbT = (short*)(ws + 16 * MB);
  short* WqT = (short*)(ws + 24 * MB);
  short* WkT = (short*)(ws + 26 * MB);
  short* WvT = (short*)(ws + 28 * MB);
  short* WoT = (short*)(ws + 30 * MB);
  short* Ob  = big ? (short*)(ws + 32 * MB)
                   : (short*)(ws + 24 * MB);

  dim3 tgrid(16, 16, big ? 4 : 3);
  wtrans<<<tgrid, 256, 0, stream>>>(Wq, Wk, Wv, Wo, WqT, WkT, WvT, big ? WoT : WqT);

  dim3 gq(DM / 64, (2 * S_LEN) / 128);
  gemm2<0, 1, 3><<<gq, 256, 0, stream>>>(query, WqT, Qb, 2 * S_LEN, DM, DM);   // Q, pre-scaled
  gemm2<0, 1, 1><<<gq, 256, 0, stream>>>(key,   WkT, Kb, 2 * S_LEN, DM, DM);
  dim3 gv((2 * S_LEN) / 64, DM / 128);
  gemm2<1, 0, 2><<<gv, 256, 0, stream>>>(WvT, value, VbT, DM, 2 * S_LEN, DM);

  dim3 ag(S_LEN / 256, 2 * NHEAD);  // (8, 32)
  attn3<<<ag, 512, 0, stream>>>(Qb, Kb, VbT, mask, Ob);

  if (big) gemm2<1, 1, 0><<<gq, 256, 0, stream>>>(Ob, WoT, (float*)d_out, 2 * S_LEN, DM, DM);
  else     gemm2<1, 2, 0><<<gq, 256, 0, stream>>>(Ob, Wo,  (float*)d_out, 2 * S_LEN, DM, DM);
}

// Round 4
// 146.141 us; speedup vs baseline: 2.8627x; 1.3410x over previous
//
#include <hip/hip_runtime.h>
#include <hip/hip_bf16.h>

typedef short bf16x8 __attribute__((ext_vector_type(8)));  // 8 bf16 (4 VGPRs)
typedef float f32x4 __attribute__((ext_vector_type(4)));

#define S_LEN 2048
#define NHEAD 16
#define DM 1024

#if __has_builtin(__builtin_amdgcn_exp2f)
#define EXP2(x) __builtin_amdgcn_exp2f(x)
#else
#define EXP2(x) exp2f(x)
#endif

__device__ __forceinline__ short f2bf(float f) {
  union { float f; unsigned u; } x; x.f = f;
  unsigned r = x.u + 0x7fffu + ((x.u >> 16) & 1u);  // RNE
  return (short)(r >> 16);
}

__device__ __forceinline__ void gload16(const void* g, void* l) {
  __builtin_amdgcn_global_load_lds(
      (const __attribute__((address_space(1))) void*)g,
      (__attribute__((address_space(3))) void*)l, 16, 0, 0);
}

// ---------------- weight transpose+convert: T[n][k] = bf16(W[k][n]), 1024x1024
__global__ __launch_bounds__(256) void wtrans(const float* __restrict__ Wq, const float* __restrict__ Wk,
                                              const float* __restrict__ Wv, const float* __restrict__ Wo,
                                              short* Tq, short* Tk, short* Tv, short* To) {
  const int z = blockIdx.z;
  const float* W = (z == 0) ? Wq : (z == 1) ? Wk : (z == 2) ? Wv : Wo;
  short* T = (z == 0) ? Tq : (z == 1) ? Tk : (z == 2) ? Tv : To;
  __shared__ short Tl[64][72];
  const int tid = threadIdx.x;
  const int k0 = blockIdx.x * 64, n0 = blockIdx.y * 64;
  const int r = tid >> 2, c0 = (tid & 3) * 16;
#pragma unroll
  for (int j = 0; j < 4; j++) {
    float4 v = *(const float4*)&W[(size_t)(k0 + r) * DM + n0 + c0 + 4 * j];
    Tl[r][c0 + 4 * j + 0] = f2bf(v.x);
    Tl[r][c0 + 4 * j + 1] = f2bf(v.y);
    Tl[r][c0 + 4 * j + 2] = f2bf(v.z);
    Tl[r][c0 + 4 * j + 3] = f2bf(v.w);
  }
  __syncthreads();
  bf16x8 o0, o1;
#pragma unroll
  for (int j = 0; j < 8; j++) { o0[j] = Tl[c0 + j][r]; o1[j] = Tl[c0 + 8 + j][r]; }
  *(bf16x8*)&T[(size_t)(n0 + r) * DM + k0 + c0] = o0;
  *(bf16x8*)&T[(size_t)(n0 + r) * DM + k0 + c0 + 8] = o1;
}

// ---------------- x f32 -> bf16 convert (3 tensors), 16 elems/thread
__global__ __launch_bounds__(256) void xcvt(const float* __restrict__ q, const float* __restrict__ k,
                                            const float* __restrict__ v,
                                            short* xq, short* xk, short* xv) {
  const int z = blockIdx.y;
  const float* src = (z == 0) ? q : (z == 1) ? k : v;
  short* dst = (z == 0) ? xq : (z == 1) ? xk : xv;
  const size_t base = ((size_t)blockIdx.x * 256 + threadIdx.x) * 16;
  float4 a = *(const float4*)&src[base];
  float4 b = *(const float4*)&src[base + 4];
  float4 c = *(const float4*)&src[base + 8];
  float4 d = *(const float4*)&src[base + 12];
  bf16x8 o0, o1;
  o0[0] = f2bf(a.x); o0[1] = f2bf(a.y); o0[2] = f2bf(a.z); o0[3] = f2bf(a.w);
  o0[4] = f2bf(b.x); o0[5] = f2bf(b.y); o0[6] = f2bf(b.z); o0[7] = f2bf(b.w);
  o1[0] = f2bf(c.x); o1[1] = f2bf(c.y); o1[2] = f2bf(c.z); o1[3] = f2bf(c.w);
  o1[4] = f2bf(d.x); o1[5] = f2bf(d.y); o1[6] = f2bf(d.z); o1[7] = f2bf(d.w);
  *(bf16x8*)&dst[base] = o0;
  *(bf16x8*)&dst[base + 8] = o1;
}

// ---------------- gemm3: all-bf16, global_load_lds dbuf, swizzled LDS.
// C(MxN) = A(MxK) @ B_op(KxN), A bf16 [m][k], Bt bf16 [n][k].
// BM=128 BN=64 BK=64, 256 thr (4 waves 2x2), per-wave 64x32 (acc 4x2).
// CM: 0=f32 row-major, 1=bf16 scatter [bh][s][64], 2=bf16 scatter [bh][64][s],
//     3=like 1 scaled by 0.125*log2e (Q proj)
template<int CM>
__global__ __launch_bounds__(256) void gemm3(const short* __restrict__ A, const short* __restrict__ Bt,
                                             void* __restrict__ Cp, int M, int N, int K) {
  __shared__ __align__(16) short Al[2][128 * 64];
  __shared__ __align__(16) short Bl[2][64 * 64];
  const int tid = threadIdx.x;
  const int lane = tid & 63, w = tid >> 6;
  const int wm = w >> 1, wn = w & 1;
  const int lr = lane & 15, g = lane >> 4;
  const int m0 = blockIdx.y * 128, n0 = blockIdx.x * 64;

  f32x4 acc[4][2];
#pragma unroll
  for (int i = 0; i < 4; i++)
#pragma unroll
    for (int j = 0; j < 2; j++) acc[i][j] = (f32x4){0.f, 0.f, 0.f, 0.f};

  // staging: lane -> row (l>>3), swizzled source chunk (l&7)^((l>>3)&7)
  const int srow = lane >> 3;
  const int sch = (lane & 7) ^ (srow & 7);
  const short* gA = A + (size_t)(m0 + w * 32 + srow) * K + 8 * sch;
  const short* gB = Bt + (size_t)(n0 + w * 16 + srow) * K + 8 * sch;

#define STAGE(buf, kk)                                                              \
  do {                                                                              \
    _Pragma("unroll") for (int c = 0; c < 4; c++)                                   \
        gload16(gA + (size_t)c * 8 * K + (kk), &Al[buf][(w * 32 + c * 8) * 64]);    \
    _Pragma("unroll") for (int c = 0; c < 2; c++)                                   \
        gload16(gB + (size_t)c * 8 * K + (kk), &Bl[buf][(w * 16 + c * 8) * 64]);    \
  } while (0)

  const int nsteps = K >> 6;
  STAGE(0, 0);
  int buf = 0;
  for (int t = 0; t < nsteps; t++) {
    __syncthreads();  // vmcnt drained: tile t resident; prior reads of buf^1 done
    if (t + 1 < nsteps) STAGE(buf ^ 1, (t + 1) << 6);
#pragma unroll
    for (int kc = 0; kc < 2; kc++) {
      bf16x8 af[4], bfr[2];
#pragma unroll
      for (int mt = 0; mt < 4; mt++) {
        int row = wm * 64 + mt * 16 + lr;
        af[mt] = *(const bf16x8*)&Al[buf][row * 64 + 8 * ((kc * 4 + g) ^ (lr & 7))];
      }
#pragma unroll
      for (int nt = 0; nt < 2; nt++) {
        int row = wn * 32 + nt * 16 + lr;
        bfr[nt] = *(const bf16x8*)&Bl[buf][row * 64 + 8 * ((kc * 4 + g) ^ (lr & 7))];
      }
      __builtin_amdgcn_s_setprio(1);
#pragma unroll
      for (int mt = 0; mt < 4; mt++)
#pragma unroll
        for (int nt = 0; nt < 2; nt++)
          acc[mt][nt] = __builtin_amdgcn_mfma_f32_16x16x32_bf16(af[mt], bfr[nt], acc[mt][nt], 0, 0, 0);
      __builtin_amdgcn_s_setprio(0);
    }
    buf ^= 1;
  }
#undef STAGE

#pragma unroll
  for (int mt = 0; mt < 4; mt++)
#pragma unroll
    for (int nt = 0; nt < 2; nt++)
#pragma unroll
      for (int r = 0; r < 4; r++) {
        int row = m0 + wm * 64 + mt * 16 + g * 4 + r;
        int col = n0 + wn * 32 + nt * 16 + lr;
        if (CM == 0) {
          ((float*)Cp)[(size_t)row * N + col] = acc[mt][nt][r];
        } else if (CM == 1 || CM == 3) {
          float v = (CM == 3) ? acc[mt][nt][r] * 0.18033688011f : acc[mt][nt][r];
          int b = row >> 11, s = row & (S_LEN - 1);
          int h = col >> 6, d = col & 63;
          ((short*)Cp)[(((size_t)(b * NHEAD + h)) * S_LEN + s) * 64 + d] = f2bf(v);
        } else {
          int h = row >> 6, d = row & 63;
          int b = col >> 11, s = col & (S_LEN - 1);
          ((short*)Cp)[(((size_t)(b * NHEAD + h)) * 64 + d) * S_LEN + s] = f2bf(acc[mt][nt][r]);
        }
      }
}

// ---------------- gemm2 (round-3 reg-staged, fallback path for small ws)
template<int AM, int BMODE, int CM>
__global__ __launch_bounds__(256) void gemm2(const void* __restrict__ Ap, const void* __restrict__ Bp,
                                             void* __restrict__ Cp, int M, int N, int K) {
  __shared__ __align__(16) short Al[128][72];
  __shared__ __align__(16) short Bl[64][72];
  const int tid = threadIdx.x;
  const int lane = tid & 63, w = tid >> 6;
  const int wm = w >> 1, wn = w & 1;
  const int lr = lane & 15, g = lane >> 4;
  const int m0 = blockIdx.y * 128, n0 = blockIdx.x * 64;

  f32x4 acc[4][2];
#pragma unroll
  for (int i = 0; i < 4; i++)
#pragma unroll
    for (int j = 0; j < 2; j++) acc[i][j] = (f32x4){0.f, 0.f, 0.f, 0.f};

  const int ar = tid >> 1, ac = (tid & 1) * 32;
  const int br = tid >> 2, bc = (tid & 3) * 16;

  float4 la[8]; bf16x8 la8[4];
  float4 lb[4]; bf16x8 lb8[2];

#define LOADA(kk)                                                                        \
  do {                                                                                   \
    if (AM == 0) {                                                                       \
      const float* A = (const float*)Ap;                                                 \
      _Pragma("unroll") for (int j = 0; j < 8; j++)                                      \
          la[j] = *(const float4*)&A[(size_t)(m0 + ar) * K + (kk) + ac + 4 * j];         \
    } else {                                                                             \
      const short* A = (const short*)Ap;                                                 \
      _Pragma("unroll") for (int j = 0; j < 4; j++)                                      \
          la8[j] = *(const bf16x8*)&A[(size_t)(m0 + ar) * K + (kk) + ac + 8 * j];        \
    }                                                                                    \
  } while (0)

#define LOADB(kk)                                                                        \
  do {                                                                                   \
    if (BMODE == 0) {                                                                    \
      const float* B = (const float*)Bp;                                                 \
      _Pragma("unroll") for (int j = 0; j < 4; j++)                                      \
          lb[j] = *(const float4*)&B[(size_t)(n0 + br) * K + (kk) + bc + 4 * j];         \
    } else if (BMODE == 1) {                                                             \
      const short* B = (const short*)Bp;                                                 \
      _Pragma("unroll") for (int j = 0; j < 2; j++)                                      \
          lb8[j] = *(const bf16x8*)&B[(size_t)(n0 + br) * K + (kk) + bc + 8 * j];        \
    } else {                                                                             \
      const float* B = (const float*)Bp;                                                 \
      _Pragma("unroll") for (int j = 0; j < 4; j++)                                      \
          lb[j] = *(const float4*)&B[(size_t)((kk) + br) * N + n0 + bc + 4 * j];         \
    }                                                                                    \
  } while (0)

  const int nsteps = K >> 6;
  LOADA(0); LOADB(0);

  for (int t = 0; t < nsteps; t++) {
    __syncthreads();
    if (AM == 0) {
#pragma unroll
      for (int j = 0; j < 4; j++) {
        float4 v0 = la[2 * j], v1 = la[2 * j + 1];
        bf16x8 tt;
        tt[0] = f2bf(v0.x); tt[1] = f2bf(v0.y); tt[2] = f2bf(v0.z); tt[3] = f2bf(v0.w);
        tt[4] = f2bf(v1.x); tt[5] = f2bf(v1.y); tt[6] = f2bf(v1.z); tt[7] = f2bf(v1.w);
        *(bf16x8*)&Al[ar][ac + 8 * j] = tt;
      }
    } else {
#pragma unroll
      for (int j = 0; j < 4; j++) *(bf16x8*)&Al[ar][ac + 8 * j] = la8[j];
    }
    if (BMODE == 0) {
#pragma unroll
      for (int j = 0; j < 2; j++) {
        float4 v0 = lb[2 * j], v1 = lb[2 * j + 1];
        bf16x8 tt;
        tt[0] = f2bf(v0.x); tt[1] = f2bf(v0.y); tt[2] = f2bf(v0.z); tt[3] = f2bf(v0.w);
        tt[4] = f2bf(v1.x); tt[5] = f2bf(v1.y); tt[6] = f2bf(v1.z); tt[7] = f2bf(v1.w);
        *(bf16x8*)&Bl[br][bc + 8 * j] = tt;
      }
    } else if (BMODE == 1) {
#pragma unroll
      for (int j = 0; j < 2; j++) *(bf16x8*)&Bl[br][bc + 8 * j] = lb8[j];
    } else {
#pragma unroll
      for (int j = 0; j < 4; j++) {
        float4 v = lb[j];
        Bl[bc + 4 * j + 0][br] = f2bf(v.x);
        Bl[bc + 4 * j + 1][br] = f2bf(v.y);
        Bl[bc + 4 * j + 2][br] = f2bf(v.z);
        Bl[bc + 4 * j + 3][br] = f2bf(v.w);
      }
    }
    __syncthreads();
    if (t + 1 < nsteps) { LOADA((t + 1) << 6); LOADB((t + 1) << 6); }
#pragma unroll
    for (int kc = 0; kc < 2; kc++) {
      bf16x8 af[4], bfr[2];
#pragma unroll
      for (int mt = 0; mt < 4; mt++) af[mt] = *(const bf16x8*)&Al[wm * 64 + mt * 16 + lr][kc * 32 + g * 8];
#pragma unroll
      for (int nt = 0; nt < 2; nt++) bfr[nt] = *(const bf16x8*)&Bl[wn * 32 + nt * 16 + lr][kc * 32 + g * 8];
#pragma unroll
      for (int mt = 0; mt < 4; mt++)
#pragma unroll
        for (int nt = 0; nt < 2; nt++)
          acc[mt][nt] = __builtin_amdgcn_mfma_f32_16x16x32_bf16(af[mt], bfr[nt], acc[mt][nt], 0, 0, 0);
    }
  }
#undef LOADA
#undef LOADB

#pragma unroll
  for (int mt = 0; mt < 4; mt++)
#pragma unroll
    for (int nt = 0; nt < 2; nt++)
#pragma unroll
      for (int r = 0; r < 4; r++) {
        int row = m0 + wm * 64 + mt * 16 + g * 4 + r;
        int col = n0 + wn * 32 + nt * 16 + lr;
        if (CM == 0) {
          ((float*)Cp)[(size_t)row * N + col] = acc[mt][nt][r];
        } else if (CM == 1 || CM == 3) {
          float v = (CM == 3) ? acc[mt][nt][r] * 0.18033688011f : acc[mt][nt][r];
          int b = row >> 11, s = row & (S_LEN - 1);
          int h = col >> 6, d = col & 63;
          ((short*)Cp)[(((size_t)(b * NHEAD + h)) * S_LEN + s) * 64 + d] = f2bf(v);
        } else {
          int h = row >> 6, d = row & 63;
          int b = col >> 11, s = col & (S_LEN - 1);
          ((short*)Cp)[(((size_t)(b * NHEAD + h)) * 64 + d) * S_LEN + s] = f2bf(acc[mt][nt][r]);
        }
      }
}

// ---------------- Flash attention v4: QBLK=128 (4 waves x 32 q), KVBLK=64,
// 2 blocks/CU, XCD-chunked swizzle, setprio around MFMA.
// Q pre-scaled by 0.125*log2e; max-free exp2 softmax, deferred row-sum.
// Q,K: [bh][s][64] bf16.  V^T: [bh][64][s] bf16.
__global__ __launch_bounds__(256, 2) void attn4(const short* __restrict__ Qb,
                                                const short* __restrict__ Kb,
                                                const short* __restrict__ VbT,
                                                const int* __restrict__ mask,
                                                short* __restrict__ Ob) {
  __shared__ __align__(16) short Kl[2][64][64];
  __shared__ __align__(16) short Vl[2][64][64];
  __shared__ __align__(16) short Pl[4][32][64];

  const int tid = threadIdx.x;
  const int lane = tid & 63, w = tid >> 6;  // 4 waves
  const int lr = lane & 15, g = lane >> 4;

  // XCD-chunked bijective swizzle: 512 blocks, 8 XCDs, 64/chunk -> 4 heads/XCD
  const int flat = blockIdx.y * gridDim.x + blockIdx.x;
  const int wid = (flat & 7) * 64 + (flat >> 3);
  const int qblk = wid & 15, bh = wid >> 4;
  const int b = bh >> 4, h = bh & 15;
  const int qbase = qblk * 128;
  const size_t hoff = (size_t)bh * S_LEN * 64;

  bf16x8 qf[2][2];
#pragma unroll
  for (int qfr = 0; qfr < 2; qfr++)
#pragma unroll
    for (int kh = 0; kh < 2; kh++)
      qf[qfr][kh] = *(const bf16x8*)&Qb[hoff + (size_t)(qbase + w * 32 + qfr * 16 + lr) * 64 + kh * 32 + g * 8];

  f32x4 o_acc[2][4];
  float lsum[2][4];
#pragma unroll
  for (int qfr = 0; qfr < 2; qfr++) {
#pragma unroll
    for (int dg = 0; dg < 4; dg++) o_acc[qfr][dg] = (f32x4){0.f, 0.f, 0.f, 0.f};
#pragma unroll
    for (int r = 0; r < 4; r++) lsum[qfr][r] = 0.f;
  }

  const int* maskb = mask + b * S_LEN;
  // staging: wave w covers 16 rows (2 calls x 8); swizzled source chunk
  const int srow = lane >> 3;
  const int sch = (lane & 7) ^ (srow & 7);
  const short* gK = Kb + hoff + (size_t)(w * 16 + srow) * 64 + 8 * sch;
  const short* gV = VbT + hoff + (size_t)(w * 16 + srow) * S_LEN + 8 * sch;

#define STAGEKV(buf, kb)                                                       \
  do {                                                                         \
    _Pragma("unroll") for (int c = 0; c < 2; c++)                              \
        gload16(gK + (size_t)(kb + c * 8) * 64, &Kl[buf][w * 16 + c * 8][0]);  \
    _Pragma("unroll") for (int c = 0; c < 2; c++)                              \
        gload16(gV + (size_t)c * 8 * S_LEN + (kb), &Vl[buf][w * 16 + c * 8][0]); \
  } while (0)

  const int NT = S_LEN / 64;
  STAGEKV(0, 0);
  int buf = 0;

  for (int t = 0; t < NT; t++) {
    const int kb = t * 64;
    __syncthreads();  // vmcnt drained: tile t resident; prior reads of buf^1 done
    if (t + 1 < NT) STAGEKV(buf ^ 1, kb + 64);

    float bias[4];
#pragma unroll
    for (int nt = 0; nt < 4; nt++) bias[nt] = maskb[kb + 16 * nt + lr] ? 0.f : -1e30f;

    // ---- QK^T
    bf16x8 kfr[4][2];
#pragma unroll
    for (int nt = 0; nt < 4; nt++)
#pragma unroll
      for (int kh = 0; kh < 2; kh++)
        kfr[nt][kh] = *(const bf16x8*)&Kl[buf][nt * 16 + lr][8 * ((4 * kh + g) ^ (lr & 7))];

    f32x4 s[2][4];
#pragma unroll
    for (int qfr = 0; qfr < 2; qfr++)
#pragma unroll
      for (int nt = 0; nt < 4; nt++) s[qfr][nt] = (f32x4){0.f, 0.f, 0.f, 0.f};
    __builtin_amdgcn_s_setprio(1);
#pragma unroll
    for (int qfr = 0; qfr < 2; qfr++)
#pragma unroll
      for (int nt = 0; nt < 4; nt++) {
        s[qfr][nt] = __builtin_amdgcn_mfma_f32_16x16x32_bf16(qf[qfr][0], kfr[nt][0], s[qfr][nt], 0, 0, 0);
        s[qfr][nt] = __builtin_amdgcn_mfma_f32_16x16x32_bf16(qf[qfr][1], kfr[nt][1], s[qfr][nt], 0, 0, 0);
      }
    __builtin_amdgcn_s_setprio(0);

    // V frags (latency hides under softmax)
    bf16x8 vfr[4][2];
#pragma unroll
    for (int dg = 0; dg < 4; dg++)
#pragma unroll
      for (int kh = 0; kh < 2; kh++)
        vfr[dg][kh] = *(const bf16x8*)&Vl[buf][dg * 16 + lr][8 * ((4 * kh + g) ^ (lr & 7))];

    // ---- softmax: p = exp2(s + bias); deferred row-sum
#pragma unroll
    for (int qfr = 0; qfr < 2; qfr++)
#pragma unroll
      for (int nt = 0; nt < 4; nt++)
#pragma unroll
        for (int r = 0; r < 4; r++) {
          float p = EXP2(s[qfr][nt][r] + bias[nt]);
          lsum[qfr][r] += p;
          union { float f; unsigned u; } cv; cv.f = p;
          unsigned short pb = (unsigned short)((cv.u + 0x7fffu) >> 16);
          int q = qfr * 16 + g * 4 + r;
          Pl[w][q][(16 * nt + lr) ^ ((q & 7) << 3)] = (short)pb;
        }

    // ---- PV
#pragma unroll
    for (int qfr = 0; qfr < 2; qfr++) {
      bf16x8 pf[2];
#pragma unroll
      for (int kh = 0; kh < 2; kh++)
        pf[kh] = *(const bf16x8*)&Pl[w][qfr * 16 + lr][8 * ((4 * kh + g) ^ (lr & 7))];
      __builtin_amdgcn_s_setprio(1);
#pragma unroll
      for (int dg = 0; dg < 4; dg++) {
        o_acc[qfr][dg] = __builtin_amdgcn_mfma_f32_16x16x32_bf16(pf[0], vfr[dg][0], o_acc[qfr][dg], 0, 0, 0);
        o_acc[qfr][dg] = __builtin_amdgcn_mfma_f32_16x16x32_bf16(pf[1], vfr[dg][1], o_acc[qfr][dg], 0, 0, 0);
      }
      __builtin_amdgcn_s_setprio(0);
    }
    buf ^= 1;
  }
#undef STAGEKV

#pragma unroll
  for (int qfr = 0; qfr < 2; qfr++)
#pragma unroll
    for (int r = 0; r < 4; r++) {
      float l = lsum[qfr][r];
#pragma unroll
      for (int off = 1; off < 16; off <<= 1) l += __shfl_xor(l, off);
      float inv = 1.f / l;
      int qr = qbase + w * 32 + qfr * 16 + g * 4 + r;
#pragma unroll
      for (int dg = 0; dg < 4; dg++) {
        int col = h * 64 + dg * 16 + lr;
        Ob[((size_t)b * S_LEN + qr) * DM + col] = f2bf(o_acc[qfr][dg][r] * inv);
      }
    }
}

extern "C" void kernel_launch(void* const* d_in, const int* in_sizes, int n_in,
                              void* d_out, int out_size, void* d_ws, size_t ws_size,
                              hipStream_t stream) {
  const float* query = (const float*)d_in[0];
  const float* key   = (const float*)d_in[1];
  const float* value = (const float*)d_in[2];
  const float* Wq = (const float*)d_in[3];
  const float* Wk = (const float*)d_in[4];
  const float* Wv = (const float*)d_in[5];
  const float* Wo = (const float*)d_in[6];
  const int* mask = (const int*)d_in[7];

  char* ws = (char*)d_ws;
  const size_t MB = 1 << 20;
  const bool big = ws_size >= 41 * MB;

  dim3 ag(S_LEN / 128, 2 * NHEAD);  // (16, 32) = 512 blocks

  if (big) {
    // layout: xq[0,8) xk[8,16) xv[16,24) W[24,32) Qb[32,40); Kb<-xq VbT<-xk Ob<-xv
    short* xq  = (short*)(ws);
    short* xk  = (short*)(ws + 8 * MB);
    short* xv  = (short*)(ws + 16 * MB);
    short* WqT = (short*)(ws + 24 * MB);
    short* WkT = (short*)(ws + 26 * MB);
    short* WvT = (short*)(ws + 28 * MB);
    short* WoT = (short*)(ws + 30 * MB);
    short* Qb  = (short*)(ws + 32 * MB);
    short* Kb  = xq;
    short* VbT = xk;
    short* Ob  = xv;

    dim3 tgrid(16, 16, 4);
    wtrans<<<tgrid, 256, 0, stream>>>(Wq, Wk, Wv, Wo, WqT, WkT, WvT, WoT);
    dim3 cg(1024, 3);
    xcvt<<<cg, 256, 0, stream>>>(query, key, value, xq, xk, xv);

    dim3 gqk(DM / 64, (2 * S_LEN) / 128);  // (16, 32)
    gemm3<3><<<gqk, 256, 0, stream>>>(xq, WqT, Qb, 2 * S_LEN, DM, DM);
    gemm3<1><<<gqk, 256, 0, stream>>>(xk, WkT, Kb, 2 * S_LEN, DM, DM);
    dim3 gv((2 * S_LEN) / 64, DM / 128);   // (64, 8)
    gemm3<2><<<gv, 256, 0, stream>>>(WvT, xv, VbT, DM, 2 * S_LEN, DM);

    attn4<<<ag, 256, 0, stream>>>(Qb, Kb, VbT, mask, Ob);

    gemm3<0><<<gqk, 256, 0, stream>>>(Ob, WoT, (float*)d_out, 2 * S_LEN, DM, DM);
  } else {
    // round-3 fallback (32 MB): Qb[0,8) Kb[8,16) VbT[16,24) W3[24,30) Ob[24,32)
    short* Qb  = (short*)(ws);
    short* Kb  = (short*)(ws + 8 * MB);
    short* VbT = (short*)(ws + 16 * MB);
    short* WqT = (short*)(ws + 24 * MB);
    short* WkT = (short*)(ws + 26 * MB);
    short* WvT = (short*)(ws + 28 * MB);
    short* Ob  = (short*)(ws + 24 * MB);  // aliases dead WqT/WkT/WvT

    dim3 tgrid(16, 16, 3);
    wtrans<<<tgrid, 256, 0, stream>>>(Wq, Wk, Wv, Wo, WqT, WkT, WvT, WqT);

    dim3 gq(DM / 64, (2 * S_LEN) / 128);
    gemm2<0, 1, 3><<<gq, 256, 0, stream>>>(query, WqT, Qb, 2 * S_LEN, DM, DM);
    gemm2<0, 1, 1><<<gq, 256, 0, stream>>>(key,   WkT, Kb, 2 * S_LEN, DM, DM);
    dim3 gv((2 * S_LEN) / 64, DM / 128);
    gemm2<1, 0, 2><<<gv, 256, 0, stream>>>(WvT, value, VbT, DM, 2 * S_LEN, DM);

    attn4<<<ag, 256, 0, stream>>>(Qb, Kb, VbT, mask, Ob);

    gemm2<1, 2, 0><<<gq, 256, 0, stream>>>(Ob, Wo, (float*)d_out, 2 * S_LEN, DM, DM);
  }
}